// Round 17
// baseline (120.383 us; speedup 1.0000x reference)
//
#include <hip/hip_runtime.h>
#include <hip/hip_bf16.h>

#define T_STEPS 100
#define D_IN    65536
#define HID     256
#define HTOT    512
#define BETA    0.95f
#define THRESH  1.0f

typedef __bf16 bf16x8 __attribute__((ext_vector_type(8)));
typedef float  f32x16 __attribute__((ext_vector_type(16)));

__device__ __forceinline__ void gload_lds16(const void* g, void* l) {
    __builtin_amdgcn_global_load_lds(
        (const __attribute__((address_space(1))) void*)g,
        (__attribute__((address_space(3))) void*)l, 16, 0, 0);
}

// ---- GEMM1 R17: BH=256 tile (x staged 2x total instead of 4x), K-step=16.
// Per 16-k step-buffer (24 KB): [0,8K) x fp32 [128 rows][4 swz 16B granules],
// [8K,24K) W fp32 [256 rows][4 swz granules]. Staged bytes/CU-step: 48 KB
// (was 64 KB) and total staged 197 MB (was 262 MB) -- tests the affine
// staging model (step = bytes/11 + 2500 cyc) built from R7..R16.
// 2-buffer gload_lds pipeline, 48 KB LDS -> 2 blocks/CU, vmcnt(3) steady.
// Block = 512 thr = 8 waves (2t x 4h), wave = 64t x 64h (2x2 f32x16 accs).
// 3-product bf16 hi/mid MFMA, k ascending. Pad t-rows clamped (discarded).
// grid 512 flat, XCD swizzle: both h-tiles of a split + 32 adjacent splits
// land on one XCD -> x served from that XCD's L2.
__global__ __launch_bounds__(512, 2) void k_gemm1(
    const float* __restrict__ aW1,   // [256][65536]
    const float* __restrict__ cW1,   // [256][65536]
    const float* __restrict__ x,     // [100][65536]
    float* __restrict__ P,           // [256][100][512]
    int nsteps)                      // 16-k steps per split (16 at NS=256)
{
    // bijective: d -> xcd = d&7, sl = d>>3; s = xcd*32 + (sl&31); ht = sl>>5
    const int d    = blockIdx.x;
    const int xcd  = d & 7;
    const int sl   = d >> 3;
    const int s    = xcd * 32 + (sl & 31);   // 0..255
    const int ht   = sl >> 5;                // 0 actor, 1 critic

    const int tid  = threadIdx.x;
    const int lane = tid & 63;
    const int l31  = lane & 31;
    const int h5   = lane >> 5;
    const int wv   = tid >> 6;           // 0..7
    const int wt   = (wv & 1) * 64;      // wave t-offset
    const int wh   = (wv >> 1) * 64;     // wave h-offset (0/64/128/192)

    __shared__ __align__(16) char smem[2][24576];   // 48 KB

    const float* Wbase = ht ? cW1 : aW1;            // full 256-row matrix

    // staging: 3 gload_lds per thread per step (512 x + 1024 W granules).
    // granule (row, g): LDS dest linear at idx*16; source col pre-swizzled
    // (g ^ (row&3))*4 floats so swizzled LDS reads land on distinct banks.
    const int xrow_raw = tid >> 2;
    const int xg       = tid & 3;
    const int xrow     = (xrow_raw < T_STEPS) ? xrow_raw : (T_STEPS - 1);
    const float* xsrc  = x + (size_t)xrow * D_IN + (xg ^ (xrow_raw & 3)) * 4;
    const float* wsrc[2];
#pragma unroll
    for (int o = 0; o < 2; o++) {
        const int idx = o * 512 + tid;
        const int row = idx >> 2, g = idx & 3;
        wsrc[o] = Wbase + (size_t)row * D_IN + (g ^ (row & 3)) * 4;
    }
    const int gk0 = s * nsteps;          // step index base (16 floats/step)

    f32x16 acc00, acc01, acc10, acc11;
#pragma unroll
    for (int i = 0; i < 16; i++) {
        acc00[i] = 0.f; acc01[i] = 0.f; acc10[i] = 0.f; acc11[i] = 0.f;
    }

#define STAGE(i) do {                                                         \
    char* b_ = smem[(i) & 1];                                                 \
    const int kc_ = (gk0 + (i)) * 16;                                         \
    gload_lds16(xsrc + kc_, b_ + tid * 16);                                   \
    gload_lds16(wsrc[0] + kc_, b_ + 8192 + tid * 16);                         \
    gload_lds16(wsrc[1] + kc_, b_ + 8192 + (512 + tid) * 16);                 \
} while (0)

#define CVT8(dsth, dstm, va, vb) do {                                         \
    float f_[8] = {va.x, va.y, va.z, va.w, vb.x, vb.y, vb.z, vb.w};           \
    _Pragma("unroll")                                                         \
    for (int e = 0; e < 8; e++) {                                             \
        __bf16 h = (__bf16)f_[e];                                             \
        dsth[e] = h; dstm[e] = (__bf16)(f_[e] - (float)h);                    \
    }                                                                         \
} while (0)

#define COMPUTE(i) do {                                                       \
    const char* b_ = smem[(i) & 1];                                           \
    const int gb = h5 * 2;                                                    \
    /* A fragments: x rows r0, r1 (k-half h5) */                              \
    const int r0 = wt + l31, r1 = r0 + 32;                                    \
    float4 xa0 = *(const float4*)(b_ + (r0 * 4 + (gb       ^ (r0 & 3))) * 16);\
    float4 xb0 = *(const float4*)(b_ + (r0 * 4 + ((gb + 1) ^ (r0 & 3))) * 16);\
    float4 xa1 = *(const float4*)(b_ + (r1 * 4 + (gb       ^ (r1 & 3))) * 16);\
    float4 xb1 = *(const float4*)(b_ + (r1 * 4 + ((gb + 1) ^ (r1 & 3))) * 16);\
    bf16x8 a0h, a0m, a1h, a1m;                                                \
    CVT8(a0h, a0m, xa0, xb0);                                                 \
    CVT8(a1h, a1m, xa1, xb1);                                                 \
    /* W fragments: rows hA, hB of the 64h quadrant */                        \
    const int hA = wh + l31, hB = hA + 32;                                    \
    const char* wl_ = b_ + 8192;                                              \
    float4 waA = *(const float4*)(wl_ + (hA * 4 + (gb       ^ (hA & 3))) * 16);\
    float4 wbA = *(const float4*)(wl_ + (hA * 4 + ((gb + 1) ^ (hA & 3))) * 16);\
    float4 waB = *(const float4*)(wl_ + (hB * 4 + (gb       ^ (hB & 3))) * 16);\
    float4 wbB = *(const float4*)(wl_ + (hB * 4 + ((gb + 1) ^ (hB & 3))) * 16);\
    bf16x8 bhA, bmA, bhB, bmB;                                                \
    CVT8(bhA, bmA, waA, wbA);                                                 \
    CVT8(bhB, bmB, waB, wbB);                                                 \
    acc00 = __builtin_amdgcn_mfma_f32_32x32x16_bf16(a0m, bhA, acc00, 0,0,0);  \
    acc00 = __builtin_amdgcn_mfma_f32_32x32x16_bf16(a0h, bmA, acc00, 0,0,0);  \
    acc00 = __builtin_amdgcn_mfma_f32_32x32x16_bf16(a0h, bhA, acc00, 0,0,0);  \
    acc01 = __builtin_amdgcn_mfma_f32_32x32x16_bf16(a0m, bhB, acc01, 0,0,0);  \
    acc01 = __builtin_amdgcn_mfma_f32_32x32x16_bf16(a0h, bmB, acc01, 0,0,0);  \
    acc01 = __builtin_amdgcn_mfma_f32_32x32x16_bf16(a0h, bhB, acc01, 0,0,0);  \
    acc10 = __builtin_amdgcn_mfma_f32_32x32x16_bf16(a1m, bhA, acc10, 0,0,0);  \
    acc10 = __builtin_amdgcn_mfma_f32_32x32x16_bf16(a1h, bmA, acc10, 0,0,0);  \
    acc10 = __builtin_amdgcn_mfma_f32_32x32x16_bf16(a1h, bhA, acc10, 0,0,0);  \
    acc11 = __builtin_amdgcn_mfma_f32_32x32x16_bf16(a1m, bhB, acc11, 0,0,0);  \
    acc11 = __builtin_amdgcn_mfma_f32_32x32x16_bf16(a1h, bmB, acc11, 0,0,0);  \
    acc11 = __builtin_amdgcn_mfma_f32_32x32x16_bf16(a1h, bhB, acc11, 0,0,0);  \
} while (0)

    STAGE(0);
    STAGE(1);
    for (int i = 0; i < nsteps; i++) {
        if (i + 1 < nsteps) asm volatile("s_waitcnt vmcnt(3)" ::: "memory");
        else                asm volatile("s_waitcnt vmcnt(0)" ::: "memory");
        __builtin_amdgcn_s_barrier();              // buf[i&1] staged for all
        __builtin_amdgcn_sched_barrier(0);
        COMPUTE(i);
        __builtin_amdgcn_s_barrier();              // all waves done with buf
        __builtin_amdgcn_sched_barrier(0);
        if (i + 2 < nsteps) STAGE(i + 2);          // rides the next step
    }
#undef STAGE
#undef CVT8
#undef COMPUTE

    // ---- store partials (t >= 100 discarded -> pad-row garbage confined)
    const int rbase = 4 * h5;
    float* Pb = P + (size_t)s * T_STEPS * HTOT;
    const int hA = ht * 256 + wh + l31;
    const int hB = hA + 32;
#pragma unroll
    for (int reg = 0; reg < 16; reg++) {
        const int row = (reg & 3) + rbase + 8 * (reg >> 2);
        const int t0  = wt + row;
        const int t1  = wt + 32 + row;
        if (t0 < T_STEPS) {
            Pb[(size_t)t0 * HTOT + hA] = acc00[reg];
            Pb[(size_t)t0 * HTOT + hB] = acc01[reg];
        }
        if (t1 < T_STEPS) {
            Pb[(size_t)t1 * HTOT + hA] = acc10[reg];
            Pb[(size_t)t1 * HTOT + hB] = acc11[reg];
        }
    }
}

// reduce partials + bias -> cur1[t][h] (float2/thread, 100 blocks);
// zeroes action accumulators + completion counter (stream-before gemm2).
__global__ __launch_bounds__(256) void k_reduce(
    const float* __restrict__ P,
    const float* __restrict__ ab1, const float* __restrict__ cb1,
    float* __restrict__ cur1, float* __restrict__ wsa,
    unsigned* __restrict__ cnt, int NS)
{
    if (blockIdx.x == 0 && threadIdx.x == 0) {
        wsa[0] = 0.f; wsa[1] = 0.f; *cnt = 0u;
    }
    int g2 = blockIdx.x * 256 + threadIdx.x;   // 0..25599
    int g  = g2 * 2;
    int h0 = g & (HTOT - 1);
    float2 sum;
    sum.x = (h0 + 0 < HID) ? ab1[h0 + 0] : cb1[h0 + 0 - HID];
    sum.y = (h0 + 1 < HID) ? ab1[h0 + 1] : cb1[h0 + 1 - HID];
    for (int ss = 0; ss < NS; ss++) {
        float2 v = *(const float2*)(P + (size_t)ss * T_STEPS * HTOT + g);
        sum.x += v.x; sum.y += v.y;
    }
    *(float2*)(cur1 + g) = sum;
}

// Merged LIF1 + GEMM2 + LIF2 + (last-block) softmax. Block per output
// neuron j (0..19 actor, 20 critic), 256 threads.
__global__ __launch_bounds__(256) void k_gemm2(
    const float* __restrict__ cur1,  // [100][512]
    const float* __restrict__ aW2, const float* __restrict__ ab2,
    const float* __restrict__ cW2, const float* __restrict__ cb2,
    float* __restrict__ wsa, unsigned* __restrict__ cnt,
    float* __restrict__ out)
{
    const int j   = blockIdx.x;      // 0..20
    const int tid = threadIdx.x;

    __shared__ float W[256];
    __shared__ unsigned long long bitsL[T_STEPS][4];
    __shared__ float c2[T_STEPS];

    const float* Wsrc = (j < 20) ? (aW2 + j * 256) : cW2;
    W[tid] = Wsrc[tid];
    const int base = (j < 20) ? 0 : 256;   // actor: 0..255, critic: 256..511
    const int w    = tid >> 6;

    // LIF1 for this block's 256 source neurons (thread = neuron)
    {
        float mem = 0.f;
        for (int tb = 0; tb < T_STEPS; tb += 10) {
            float c[10];
#pragma unroll
            for (int i = 0; i < 10; i++)
                c[i] = cur1[(size_t)(tb + i) * HTOT + base + tid];
#pragma unroll
            for (int i = 0; i < 10; i++) {
                float reset = (mem > THRESH) ? THRESH : 0.f;
                mem = BETA * mem + c[i] - reset;
                unsigned long long m = __ballot(mem > THRESH);
                if ((tid & 63) == 0) bitsL[tb + i][w] = m;
            }
        }
    }
    __syncthreads();

    // GEMM2: thread = timestep; W reads are LDS broadcasts
    if (tid < T_STEPS) {
        unsigned long long m0 = bitsL[tid][0];
        unsigned long long m1 = bitsL[tid][1];
        unsigned long long m2 = bitsL[tid][2];
        unsigned long long m3 = bitsL[tid][3];
        float acc = (j < 20) ? ab2[j] : cb2[0];
#pragma unroll
        for (int b = 0; b < 64; b++) {
            acc += ((m0 >> b) & 1ULL) ? W[b]       : 0.f;
            acc += ((m1 >> b) & 1ULL) ? W[64 + b]  : 0.f;
            acc += ((m2 >> b) & 1ULL) ? W[128 + b] : 0.f;
            acc += ((m3 >> b) & 1ULL) ? W[192 + b] : 0.f;
        }
        c2[tid] = acc;
    }
    __syncthreads();

    // LIF2 + action-sum atomics + last-block softmax
    if (tid == 0) {
        float mem = 0.f, spk = 0.f;
        for (int t = 0; t < T_STEPS; t++) {
            float reset = (mem > THRESH) ? THRESH : 0.f;
            mem = BETA * mem + c2[t] - reset;
            spk += (mem > THRESH) ? 1.f : 0.f;
        }
        if (j < 10)       atomicAdd(&wsa[0], spk);   // exact: integer floats
        else if (j < 20)  atomicAdd(&wsa[1], spk);
        else              out[2] = mem;              // critic final membrane
        __threadfence();
        unsigned done = atomicAdd(cnt, 1u);
        if (done == 20u) {                           // last of 21 blocks
            float a0 = atomicAdd(&wsa[0], 0.f);      // device-scope reads
            float a1 = atomicAdd(&wsa[1], 0.f);
            float mx = fmaxf(a0, a1);
            float e0 = expf(a0 - mx), e1 = expf(a1 - mx);
            float inv = 1.f / (e0 + e1);
            out[0] = e0 * inv;
            out[1] = e1 * inv;
        }
    }
}

extern "C" void kernel_launch(void* const* d_in, const int* in_sizes, int n_in,
                              void* d_out, int out_size, void* d_ws, size_t ws_size,
                              hipStream_t stream) {
    const float* x   = (const float*)d_in[0];
    const float* aW1 = (const float*)d_in[1];
    const float* ab1 = (const float*)d_in[2];
    const float* aW2 = (const float*)d_in[3];
    const float* ab2 = (const float*)d_in[4];
    const float* cW1 = (const float*)d_in[5];
    const float* cb1 = (const float*)d_in[6];
    const float* cW2 = (const float*)d_in[7];
    const float* cb2 = (const float*)d_in[8];
    float* out = (float*)d_out;

    const int NS = 256;                                    // k-splits (swizzle assumes 256)
    const int nsteps = (D_IN / NS) / 16;                   // 16 steps of 16 k-cols

    float* P    = (float*)d_ws;                            // [256][100][512]
    float* cur1 = P + (size_t)NS * T_STEPS * HTOT;         // [100][512]
    float* wsa  = cur1 + T_STEPS * HTOT;                   // [2]
    unsigned* cnt = (unsigned*)(wsa + 2);                  // [1]

    k_gemm1 <<<512, 512, 0, stream>>>(aW1, cW1, x, P, nsteps);
    k_reduce<<<(T_STEPS * HTOT / 2) / 256, 256, 0, stream>>>(P, ab1, cb1, cur1, wsa, cnt, NS);
    k_gemm2 <<<21, 256, 0, stream>>>(cur1, aW2, ab2, cW2, cb2, wsa, cnt, out);
}

// Round 18
// 88.198 us; speedup vs baseline: 1.3649x; 1.3649x over previous
//
#include <hip/hip_runtime.h>
#include <hip/hip_bf16.h>

#define T_STEPS 100
#define D_IN    65536
#define HID     256
#define HTOT    512
#define BETA    0.95f
#define THRESH  1.0f

typedef __bf16 bf16x8 __attribute__((ext_vector_type(8)));
typedef float  f32x16 __attribute__((ext_vector_type(16)));

__device__ __forceinline__ void gload_lds16(const void* g, void* l) {
    __builtin_amdgcn_global_load_lds(
        (const __attribute__((address_space(1))) void*)g,
        (__attribute__((address_space(3))) void*)l, 16, 0, 0);
}

// ---- GEMM1 (R15/R16 measured-best config, restored).
// x + W staged fp32 via global_load_lds, converted to bf16 hi/mid in-COMPUTE.
// 2-buffer pipeline, 64 KB LDS -> 2 blocks/CU, counted vmcnt(8).
// Per 32-k step-buffer (32 KB): [0,16K) x fp32 [128 rows][8 swz granules],
// [16K,32K) W fp32 (same layout). Pad rows clamped to row 99 (garbage
// discarded at store). 3-product bf16 hi/mid MFMA.
// Block = 256 thr = 4 waves, wave owns 64t x 64h quadrant (2x2 accs).
// XCD-locality flat-grid swizzle (same-split h-tiles share an XCD's L2).
__global__ __launch_bounds__(256, 2) void k_gemm1(
    const float* __restrict__ aW1,   // [256][65536]
    const float* __restrict__ cW1,   // [256][65536]
    const float* __restrict__ x,     // [100][65536]
    float* __restrict__ P,           // [NS][100][512]
    int nsteps)                      // 32-k steps per split (16 at NS=128)
{
    // bijective swizzle: d -> xcd = d%8, slot = d/8, s = xcd*16+(slot&15), ht = slot>>4
    const int d    = blockIdx.x;
    const int xcd  = d & 7;
    const int sl   = d >> 3;
    const int s    = xcd * 16 + (sl & 15);
    const int ht   = sl >> 4;

    const int tid  = threadIdx.x;
    const int lane = tid & 63;
    const int l31  = lane & 31;
    const int h5   = lane >> 5;
    const int wv   = tid >> 6;           // 0..3
    const int wt   = (wv & 1) * 64;      // wave t-offset
    const int wh   = (wv >> 1) * 64;     // wave h-offset (64-wide quadrant)

    __shared__ __align__(16) char smem[2][32768];   // 64 KB

    const float* Wbase = (ht < 2) ? (aW1 + (size_t)ht * 128 * D_IN)
                                  : (cW1 + (size_t)(ht - 2) * 128 * D_IN);

    const float* xsrc[4];
    const float* wsrc[4];
#pragma unroll
    for (int o = 0; o < 4; o++) {
        const int idx = o * 256 + tid;
        const int row = idx >> 3, g = idx & 7;
        const int xrow = (row < T_STEPS) ? row : (T_STEPS - 1);  // clamp: pad rows discarded at store
        xsrc[o] = x     + (size_t)xrow * D_IN + (g ^ (row & 7)) * 4;
        wsrc[o] = Wbase + (size_t)row  * D_IN + (g ^ (row & 7)) * 4;
    }
    const int gk0 = s * nsteps;

    f32x16 acc00, acc01, acc10, acc11;
#pragma unroll
    for (int i = 0; i < 16; i++) {
        acc00[i] = 0.f; acc01[i] = 0.f; acc10[i] = 0.f; acc11[i] = 0.f;
    }

#define STAGE(i) do {                                                         \
    char* b_ = smem[(i) & 1];                                                 \
    const int kc_ = (gk0 + (i)) * 32;                                         \
    _Pragma("unroll")                                                         \
    for (int o = 0; o < 4; o++) {                                             \
        const int g_ = o * 256 + tid;                                         \
        gload_lds16(xsrc[o] + kc_, b_ + g_ * 16);                             \
    }                                                                         \
    _Pragma("unroll")                                                         \
    for (int o = 0; o < 4; o++) {                                             \
        const int g_ = o * 256 + tid;                                         \
        gload_lds16(wsrc[o] + kc_, b_ + 16384 + g_ * 16);                     \
    }                                                                         \
} while (0)

#define CVT8(dsth, dstm, va, vb) do {                                         \
    float f_[8] = {va.x, va.y, va.z, va.w, vb.x, vb.y, vb.z, vb.w};           \
    _Pragma("unroll")                                                         \
    for (int e = 0; e < 8; e++) {                                             \
        __bf16 h = (__bf16)f_[e];                                             \
        dsth[e] = h; dstm[e] = (__bf16)(f_[e] - (float)h);                    \
    }                                                                         \
} while (0)

#define COMPUTE(i) do {                                                       \
    const char* b_ = smem[(i) & 1];                                           \
    _Pragma("unroll")                                                         \
    for (int s16 = 0; s16 < 2; s16++) {                                       \
        const int slot_ = s16 * 2 + h5;                                       \
        const int gb    = slot_ * 2;                                          \
        const int r0 = wt + l31, r1 = r0 + 32;                                \
        const char* xr0_ = b_ + r0 * 128;                                     \
        const char* xr1_ = b_ + r1 * 128;                                     \
        float4 xa0 = *(const float4*)(xr0_ + ((gb ^ (r0 & 7)) * 16));         \
        float4 xb0 = *(const float4*)(xr0_ + (((gb + 1) ^ (r0 & 7)) * 16));   \
        float4 xa1 = *(const float4*)(xr1_ + ((gb ^ (r1 & 7)) * 16));         \
        float4 xb1 = *(const float4*)(xr1_ + (((gb + 1) ^ (r1 & 7)) * 16));   \
        bf16x8 a0h, a0m, a1h, a1m;                                            \
        CVT8(a0h, a0m, xa0, xb0);                                             \
        CVT8(a1h, a1m, xa1, xb1);                                             \
        const int hrA = wh + l31, hrB = hrA + 32;                             \
        const char* wrA_ = b_ + 16384 + hrA * 128;                            \
        const char* wrB_ = b_ + 16384 + hrB * 128;                            \
        float4 waA = *(const float4*)(wrA_ + ((gb ^ (hrA & 7)) * 16));        \
        float4 wbA = *(const float4*)(wrA_ + (((gb + 1) ^ (hrA & 7)) * 16));  \
        float4 waB = *(const float4*)(wrB_ + ((gb ^ (hrB & 7)) * 16));        \
        float4 wbB = *(const float4*)(wrB_ + (((gb + 1) ^ (hrB & 7)) * 16));  \
        bf16x8 bhA, bmA, bhB, bmB;                                            \
        CVT8(bhA, bmA, waA, wbA);                                             \
        CVT8(bhB, bmB, waB, wbB);                                             \
        acc00 = __builtin_amdgcn_mfma_f32_32x32x16_bf16(a0m, bhA, acc00, 0,0,0); \
        acc00 = __builtin_amdgcn_mfma_f32_32x32x16_bf16(a0h, bmA, acc00, 0,0,0); \
        acc00 = __builtin_amdgcn_mfma_f32_32x32x16_bf16(a0h, bhA, acc00, 0,0,0); \
        acc01 = __builtin_amdgcn_mfma_f32_32x32x16_bf16(a0m, bhB, acc01, 0,0,0); \
        acc01 = __builtin_amdgcn_mfma_f32_32x32x16_bf16(a0h, bmB, acc01, 0,0,0); \
        acc01 = __builtin_amdgcn_mfma_f32_32x32x16_bf16(a0h, bhB, acc01, 0,0,0); \
        acc10 = __builtin_amdgcn_mfma_f32_32x32x16_bf16(a1m, bhA, acc10, 0,0,0); \
        acc10 = __builtin_amdgcn_mfma_f32_32x32x16_bf16(a1h, bmA, acc10, 0,0,0); \
        acc10 = __builtin_amdgcn_mfma_f32_32x32x16_bf16(a1h, bhA, acc10, 0,0,0); \
        acc11 = __builtin_amdgcn_mfma_f32_32x32x16_bf16(a1m, bhB, acc11, 0,0,0); \
        acc11 = __builtin_amdgcn_mfma_f32_32x32x16_bf16(a1h, bmB, acc11, 0,0,0); \
        acc11 = __builtin_amdgcn_mfma_f32_32x32x16_bf16(a1h, bhB, acc11, 0,0,0); \
    }                                                                         \
} while (0)

    STAGE(0);
    STAGE(1);
    for (int i = 0; i < nsteps; i++) {
        if (i + 1 < nsteps) asm volatile("s_waitcnt vmcnt(8)" ::: "memory");
        else                asm volatile("s_waitcnt vmcnt(0)" ::: "memory");
        __builtin_amdgcn_s_barrier();              // buf[i&1] staged for all
        __builtin_amdgcn_sched_barrier(0);
        COMPUTE(i);
        __builtin_amdgcn_s_barrier();              // all waves done with buf[i&1]
        __builtin_amdgcn_sched_barrier(0);
        if (i + 2 < nsteps) STAGE(i + 2);          // rides the next step
    }
#undef STAGE
#undef CVT8
#undef COMPUTE

    // ---- store partials (t >= 100 discarded -> pad-row garbage never escapes)
    const int rbase = 4 * h5;
    float* Pb = P + (size_t)s * T_STEPS * HTOT;
    const int hA = ht * 128 + wh + l31;
    const int hB = hA + 32;
#pragma unroll
    for (int reg = 0; reg < 16; reg++) {
        const int row = (reg & 3) + rbase + 8 * (reg >> 2);
        const int t0  = wt + row;
        const int t1  = wt + 32 + row;
        if (t0 < T_STEPS) {
            Pb[(size_t)t0 * HTOT + hA] = acc00[reg];
            Pb[(size_t)t0 * HTOT + hB] = acc01[reg];
        }
        if (t1 < T_STEPS) {
            Pb[(size_t)t1 * HTOT + hA] = acc10[reg];
            Pb[(size_t)t1 * HTOT + hB] = acc11[reg];
        }
    }
}

// reduce partials + bias -> cur1[t][h] (float2/thread, 100 blocks for TLP);
// zeroes the action accumulators + completion counter (stream-before gemm2).
__global__ __launch_bounds__(256) void k_reduce(
    const float* __restrict__ P,
    const float* __restrict__ ab1, const float* __restrict__ cb1,
    float* __restrict__ cur1, float* __restrict__ wsa,
    unsigned* __restrict__ cnt, int NS)
{
    if (blockIdx.x == 0 && threadIdx.x == 0) {
        wsa[0] = 0.f; wsa[1] = 0.f; *cnt = 0u;
    }
    int g2 = blockIdx.x * 256 + threadIdx.x;   // 0..25599
    int g  = g2 * 2;
    int h0 = g & (HTOT - 1);
    float2 sum;
    sum.x = (h0 + 0 < HID) ? ab1[h0 + 0] : cb1[h0 + 0 - HID];
    sum.y = (h0 + 1 < HID) ? ab1[h0 + 1] : cb1[h0 + 1 - HID];
    for (int ss = 0; ss < NS; ss++) {
        float2 v = *(const float2*)(P + (size_t)ss * T_STEPS * HTOT + g);
        sum.x += v.x; sum.y += v.y;
    }
    *(float2*)(cur1 + g) = sum;
}

// Merged LIF1 + GEMM2 + LIF2 + (last-block) softmax.
// Block per output neuron j (0..19 actor, 20 critic), 256 threads.
__global__ __launch_bounds__(256) void k_gemm2(
    const float* __restrict__ cur1,  // [100][512]
    const float* __restrict__ aW2, const float* __restrict__ ab2,
    const float* __restrict__ cW2, const float* __restrict__ cb2,
    float* __restrict__ wsa, unsigned* __restrict__ cnt,
    float* __restrict__ out)
{
    const int j   = blockIdx.x;      // 0..20
    const int tid = threadIdx.x;

    __shared__ float W[256];
    __shared__ unsigned long long bitsL[T_STEPS][4];
    __shared__ float c2[T_STEPS];

    const float* Wsrc = (j < 20) ? (aW2 + j * 256) : cW2;
    W[tid] = Wsrc[tid];
    const int base = (j < 20) ? 0 : 256;   // actor: neurons 0..255, critic: 256..511
    const int w    = tid >> 6;

    // LIF1 for this block's 256 source neurons (thread = neuron)
    {
        float mem = 0.f;
        for (int tb = 0; tb < T_STEPS; tb += 10) {
            float c[10];
#pragma unroll
            for (int i = 0; i < 10; i++)
                c[i] = cur1[(size_t)(tb + i) * HTOT + base + tid];
#pragma unroll
            for (int i = 0; i < 10; i++) {
                float reset = (mem > THRESH) ? THRESH : 0.f;
                mem = BETA * mem + c[i] - reset;
                unsigned long long m = __ballot(mem > THRESH);
                if ((tid & 63) == 0) bitsL[tb + i][w] = m;
            }
        }
    }
    __syncthreads();

    // GEMM2: thread = timestep; W reads are LDS broadcasts
    if (tid < T_STEPS) {
        unsigned long long m0 = bitsL[tid][0];
        unsigned long long m1 = bitsL[tid][1];
        unsigned long long m2 = bitsL[tid][2];
        unsigned long long m3 = bitsL[tid][3];
        float acc = (j < 20) ? ab2[j] : cb2[0];
#pragma unroll
        for (int b = 0; b < 64; b++) {
            acc += ((m0 >> b) & 1ULL) ? W[b]       : 0.f;
            acc += ((m1 >> b) & 1ULL) ? W[64 + b]  : 0.f;
            acc += ((m2 >> b) & 1ULL) ? W[128 + b] : 0.f;
            acc += ((m3 >> b) & 1ULL) ? W[192 + b] : 0.f;
        }
        c2[tid] = acc;
    }
    __syncthreads();

    // LIF2 + action-sum atomics + last-block softmax
    if (tid == 0) {
        float mem = 0.f, spk = 0.f;
        for (int t = 0; t < T_STEPS; t++) {
            float reset = (mem > THRESH) ? THRESH : 0.f;
            mem = BETA * mem + c2[t] - reset;
            spk += (mem > THRESH) ? 1.f : 0.f;
        }
        if (j < 10)       atomicAdd(&wsa[0], spk);   // exact: integer-valued floats
        else if (j < 20)  atomicAdd(&wsa[1], spk);
        else              out[2] = mem;              // critic final membrane
        __threadfence();
        unsigned done = atomicAdd(cnt, 1u);
        if (done == 20u) {                           // last of 21 blocks
            float a0 = atomicAdd(&wsa[0], 0.f);      // device-scope reads
            float a1 = atomicAdd(&wsa[1], 0.f);
            float mx = fmaxf(a0, a1);
            float e0 = expf(a0 - mx), e1 = expf(a1 - mx);
            float inv = 1.f / (e0 + e1);
            out[0] = e0 * inv;
            out[1] = e1 * inv;
        }
    }
}

extern "C" void kernel_launch(void* const* d_in, const int* in_sizes, int n_in,
                              void* d_out, int out_size, void* d_ws, size_t ws_size,
                              hipStream_t stream) {
    const float* x   = (const float*)d_in[0];
    const float* aW1 = (const float*)d_in[1];
    const float* ab1 = (const float*)d_in[2];
    const float* aW2 = (const float*)d_in[3];
    const float* ab2 = (const float*)d_in[4];
    const float* cW1 = (const float*)d_in[5];
    const float* cb1 = (const float*)d_in[6];
    const float* cW2 = (const float*)d_in[7];
    const float* cb2 = (const float*)d_in[8];
    float* out = (float*)d_out;

    const int NS = 128;                                    // fixed (swizzle assumes 128)
    const int nsteps = (D_IN / NS) / 32;                   // 16

    float* P    = (float*)d_ws;                            // [128][100][512]
    float* cur1 = P + (size_t)NS * T_STEPS * HTOT;         // [100][512]
    float* wsa  = cur1 + T_STEPS * HTOT;                   // [2]
    unsigned* cnt = (unsigned*)(wsa + 2);                  // [1]

    k_gemm1 <<<512, 256, 0, stream>>>(aW1, cW1, x, P, nsteps);
    k_reduce<<<(T_STEPS * HTOT / 2) / 256, 256, 0, stream>>>(P, ab1, cb1, cur1, wsa, cnt, NS);
    k_gemm2 <<<21, 256, 0, stream>>>(cur1, aW2, ab2, cW2, cb2, wsa, cnt, out);
}